// Round 5
// baseline (177.833 us; speedup 1.0000x reference)
//
#include <hip/hip_runtime.h>
#include <hip/hip_bf16.h>

#define NB 1024
#define NH 256
#define EMB 128
#define TWOD 256
#define HID 256
#define ROWS 64             // history rows per block
#define BPB 4               // blocks per batch element
#define NBLK (NB * BPB)

typedef __attribute__((ext_vector_type(4))) float f32x4;
typedef __attribute__((ext_vector_type(8))) short bf16x8;

__device__ __forceinline__ unsigned short f2bf(float f) {
  union { float f; unsigned u; } v; v.f = f;
  unsigned u = v.u;
  unsigned r = (u + 0x7fffu + ((u >> 16) & 1u)) >> 16;
  return (unsigned short)r;
}

// W1 [d=256][n=256] fp32 -> W1T [n][d] bf16 (B-fragment: n-major, k contiguous)
__global__ __launch_bounds__(256) void prep_w1t(const float* __restrict__ W1,
                                                unsigned short* __restrict__ W1T) {
  const int d = blockIdx.x;
  const int n = threadIdx.x;
  W1T[(size_t)n * TWOD + d] = f2bf(W1[(size_t)d * HID + n]);
}

// tgtv[b][0..255] = concat(E_targ[target[b]], E_reg[tregion[b]])
__global__ __launch_bounds__(256) void prep_tgt(const int* __restrict__ target,
                                                const int* __restrict__ tregion,
                                                const float* __restrict__ E_targ,
                                                const float* __restrict__ E_reg,
                                                float* __restrict__ tgtv) {
  const int b = blockIdx.x;
  const int c = threadIdx.x;
  float v = (c < EMB) ? E_targ[(size_t)target[b] * EMB + c]
                      : E_reg[(size_t)tregion[b] * EMB + (c - EMB)];
  tgtv[(size_t)b * TWOD + c] = v;
}

// 4096 blocks (4 per batch element), 512 threads = 8 waves, 64 rows per block.
// Operating point: VGPR<=64, 8 waves/SIMD, 4 blocks/CU -> 32 waves/CU (100%).
// Latency hiding comes from TLP, not register depth.
// Phase 1: wave-cooperative coalesced gather, 8 rows per wave
//          (lanes 0..31 one contiguous E_hist row, lanes 32..63 the E_reg row).
// Phase 2: each wave owns one 32-col W1T strip (single pass); per-kk W1T loads
//          come from L2 and are hidden by the 8-wave round-robin.
// Phase 3: masked exp + partial (sum e, sum e*dot) -> per-block ws slots.
__global__ __launch_bounds__(512, 8) void nais_main(
    const int* __restrict__ history, const int* __restrict__ target,
    const int* __restrict__ hregion,
    const float* __restrict__ E_hist, const float* __restrict__ E_reg,
    const unsigned short* __restrict__ W1T, const float* __restrict__ b1,
    const float* __restrict__ w2, const float* __restrict__ tgtv,
    float* __restrict__ part_se, float* __restrict__ part_sd)
{
  const int blk = blockIdx.x;
  const int b = blk >> 2;
  const int r0 = (blk & 3) * ROWS;      // row offset within the 256-history
  const int tid = threadIdx.x;
  const int lane = tid & 63;
  const int wave = tid >> 6;            // 0..7
  const int l15 = lane & 15;
  const int lhi = lane >> 4;
  const int l31 = lane & 31;
  const int halfsel = lane >> 5;        // 0: E_hist half, 1: E_reg half

  __shared__ __align__(16) unsigned short inp_lds[ROWS * 256];  // 32 KiB, swizzled
  __shared__ float dot_lds[ROWS];
  __shared__ float score_parts[8][ROWS];

  const int tgt_item = target[b];

  // ---- Phase 1: coalesced gather + multiply + bf16 tile + row sums ----
  {
    const f32x4 t = *(const f32x4*)(tgtv + (size_t)b * TWOD + halfsel * EMB + l31 * 4);
    const int* keysrc = halfsel ? hregion : history;
    const float* table = halfsel ? E_reg : E_hist;

    int key[8];
    #pragma unroll
    for (int s = 0; s < 8; ++s)
      key[s] = keysrc[b * NH + r0 + wave * 8 + s];

    f32x4 vb[8];
    #pragma unroll
    for (int s = 0; s < 8; ++s)
      vb[s] = *(const f32x4*)(table + (size_t)key[s] * EMB + l31 * 4);

    #pragma unroll
    for (int s = 0; s < 8; ++s) {
      const int row = wave * 8 + s;
      f32x4 v = vb[s] * t;
      float ds = v[0] + v[1] + v[2] + v[3];
      ds += __shfl_xor(ds, 1);
      ds += __shfl_xor(ds, 2);
      ds += __shfl_xor(ds, 4);
      ds += __shfl_xor(ds, 8);
      ds += __shfl_xor(ds, 16);
      ds += __shfl_xor(ds, 32);         // combine E_hist + E_reg halves
      if (lane == 0) dot_lds[row] = ds;

      float2 f01; f01.x = v[0]; f01.y = v[1];
      float2 f23; f23.x = v[2]; f23.y = v[3];
      __hip_bfloat162 p0 = __float22bfloat162_rn(f01);
      __hip_bfloat162 p1 = __float22bfloat162_rn(f23);
      union { __hip_bfloat162 h; unsigned u; } c0, c1;
      c0.h = p0; c1.h = p1;
      const int g = halfsel * 16 + (l31 >> 1);          // 16B granule 0..31
      const int gs = g ^ (row & 7) ^ ((g >> 3) & 3);    // swizzle (bijective/row)
      unsigned* dst = (unsigned*)&inp_lds[row * 256 + gs * 8 + (lane & 1) * 4];
      dst[0] = c0.u; dst[1] = c1.u;
    }
  }
  __syncthreads();

  // ---- Phase 2: GEMM. wave owns cols [wave*32, wave*32+32) ----
  {
    const int col0 = wave * 32;
    float b1v[2], w2v[2];
    #pragma unroll
    for (int n = 0; n < 2; ++n) {
      const int colh = col0 + n * 16 + l15;
      b1v[n] = b1[colh];
      w2v[n] = w2[colh];
    }

    f32x4 acc[4][2];
    #pragma unroll
    for (int m = 0; m < 4; ++m)
      #pragma unroll
      for (int n = 0; n < 2; ++n)
        acc[m][n] = (f32x4){0.f, 0.f, 0.f, 0.f};

    #pragma unroll
    for (int kk = 0; kk < 8; ++kk) {
      bf16x8 bfr[2];
      #pragma unroll
      for (int n = 0; n < 2; ++n) {
        const int colh = col0 + n * 16 + l15;
        bfr[n] = *(const bf16x8*)(W1T + (size_t)colh * TWOD + kk * 32 + lhi * 8);
      }
      bf16x8 af[4];
      #pragma unroll
      for (int m = 0; m < 4; ++m) {
        const int row = m * 16 + l15;
        const int gk = kk * 4 + lhi;
        const int gs = gk ^ (row & 7) ^ ((gk >> 3) & 3);
        af[m] = *(const bf16x8*)(&inp_lds[row * 256 + gs * 8]);
      }
      __builtin_amdgcn_s_setprio(1);
      #pragma unroll
      for (int m = 0; m < 4; ++m)
        #pragma unroll
        for (int n = 0; n < 2; ++n)
          acc[m][n] = __builtin_amdgcn_mfma_f32_16x16x32_bf16(af[m], bfr[n], acc[m][n], 0, 0, 0);
      __builtin_amdgcn_s_setprio(0);
    }

    // epilogue: relu + b1, dot with w2, reduce 32 cols -> score_parts[wave][row]
    #pragma unroll
    for (int m = 0; m < 4; ++m) {
      #pragma unroll
      for (int r = 0; r < 4; ++r) {
        float p = 0.f;
        #pragma unroll
        for (int n = 0; n < 2; ++n) {
          float hv = acc[m][n][r] + b1v[n];   // C/D: col=lane&15, row=(lane>>4)*4+r
          hv = hv > 0.f ? hv : 0.f;
          p += hv * w2v[n];
        }
        p += __shfl_xor(p, 1);
        p += __shfl_xor(p, 2);
        p += __shfl_xor(p, 4);
        p += __shfl_xor(p, 8);
        if (l15 == 0) score_parts[wave][m * 16 + lhi * 4 + r] = p;
      }
    }
  }
  __syncthreads();

  // ---- Phase 3: masked exp + partial sums -> per-block ws slots ----
  if (wave == 0) {
    float sc = 0.f;
    #pragma unroll
    for (int w = 0; w < 8; ++w) sc += score_parts[w][lane];
    const int item = history[b * NH + r0 + lane];
    float e = (item != tgt_item) ? expf(sc) : 0.f;
    float ed = e * dot_lds[lane];
    #pragma unroll
    for (int off = 32; off >= 1; off >>= 1) {
      e += __shfl_xor(e, off);
      ed += __shfl_xor(ed, off);
    }
    if (lane == 0) {
      part_se[blk] = e;
      part_sd[blk] = ed;
    }
  }
}

__global__ __launch_bounds__(256) void finalize(const float* __restrict__ part_se,
                                                const float* __restrict__ part_sd,
                                                float* __restrict__ out) {
  const int b = blockIdx.x * 256 + threadIdx.x;
  if (b < NB) {
    float se = 0.f, sd = 0.f;
    #pragma unroll
    for (int i = 0; i < BPB; ++i) {
      se += part_se[b * BPB + i];
      sd += part_sd[b * BPB + i];
    }
    const float pred = (se > 0.f) ? (sd / sqrtf(se)) : 0.f;  // denom = sum^0.5
    out[b] = 1.f / (1.f + expf(-pred));
  }
}

extern "C" void kernel_launch(void* const* d_in, const int* in_sizes, int n_in,
                              void* d_out, int out_size, void* d_ws, size_t ws_size,
                              hipStream_t stream) {
  const int* history = (const int*)d_in[0];
  const int* target  = (const int*)d_in[1];
  const int* hregion = (const int*)d_in[2];
  const int* tregion = (const int*)d_in[3];
  const float* E_hist = (const float*)d_in[4];
  const float* E_targ = (const float*)d_in[5];
  const float* E_reg  = (const float*)d_in[6];
  const float* W1 = (const float*)d_in[7];
  const float* b1 = (const float*)d_in[8];
  const float* w2 = (const float*)d_in[9];
  float* out = (float*)d_out;

  unsigned short* W1T = (unsigned short*)d_ws;
  char* p = (char*)d_ws + (size_t)TWOD * HID * sizeof(unsigned short);
  float* tgtv = (float*)p;           p += (size_t)NB * TWOD * sizeof(float);
  float* part_se = (float*)p;        p += (size_t)NBLK * sizeof(float);
  float* part_sd = (float*)p;

  prep_w1t<<<TWOD, HID, 0, stream>>>(W1, W1T);
  prep_tgt<<<NB, TWOD, 0, stream>>>(target, tregion, E_targ, E_reg, tgtv);
  nais_main<<<NBLK, 512, 0, stream>>>(history, target, hregion, E_hist, E_reg,
                                      W1T, b1, w2, tgtv, part_se, part_sd);
  finalize<<<(NB + 255) / 256, 256, 0, stream>>>(part_se, part_sd, out);
}

// Round 6
// 106.543 us; speedup vs baseline: 1.6691x; 1.6691x over previous
//
#include <hip/hip_runtime.h>
#include <hip/hip_bf16.h>

#define NB 1024
#define NH 256
#define EMB 128
#define TWOD 256
#define HID 256
#define TROWS 64            // rows per tile
#define NT 4                // tiles per batch element

typedef __attribute__((ext_vector_type(4))) float f32x4;
typedef __attribute__((ext_vector_type(8))) short bf16x8;

__device__ __forceinline__ unsigned short f2bf(float f) {
  union { float f; unsigned u; } v; v.f = f;
  unsigned u = v.u;
  unsigned r = (u + 0x7fffu + ((u >> 16) & 1u)) >> 16;
  return (unsigned short)r;
}

// W1 [d=256][n=256] fp32 -> W1T [n][d] bf16 (B-fragment: n-major, k contiguous)
__global__ __launch_bounds__(256) void prep_w1t(const float* __restrict__ W1,
                                                unsigned short* __restrict__ W1T) {
  const int d = blockIdx.x;
  const int n = threadIdx.x;
  W1T[(size_t)n * TWOD + d] = f2bf(W1[(size_t)d * HID + n]);
}

// One block (512 threads = 8 waves) per batch element; 4 pipelined tiles of 64 rows.
// Iter t: [issue keys t+1] [wave7: fold scores t-1] [GEMM t] [issue row gathers t+1]
//         [epilogue -> score_lds] [convert+write LDS tile t+1] [barrier]
// The live next-tile gather registers force the ~128-VGPR tier (defeats the
// 64-reg remat tier that exposed L2 latency in rounds 3-5).
__global__ __launch_bounds__(512, 4) void nais_main(
    const int* __restrict__ history, const int* __restrict__ target,
    const int* __restrict__ hregion, const int* __restrict__ tregion,
    const float* __restrict__ E_hist, const float* __restrict__ E_targ,
    const float* __restrict__ E_reg,
    const unsigned short* __restrict__ W1T, const float* __restrict__ b1,
    const float* __restrict__ w2, float* __restrict__ out)
{
  const int b = blockIdx.x;
  const int tid = threadIdx.x;
  const int lane = tid & 63;
  const int wave = tid >> 6;            // 0..7
  const int l15 = lane & 15;
  const int lhi = lane >> 4;
  const int l31 = lane & 31;
  const int halfsel = lane >> 5;        // 0: E_hist/E_targ half, 1: E_reg half

  __shared__ __align__(16) unsigned short inp_lds[2][TROWS * 256];  // 64 KiB
  __shared__ float dot_lds[NT][TROWS];                              // 1 KiB
  __shared__ float score_lds[2][8][TROWS];                          // 4 KiB

  // --- per-lane target vector slice (4 floats), loaded directly ---
  const float* tsrc = halfsel ? (E_reg + (size_t)tregion[b] * EMB)
                              : (E_targ + (size_t)target[b] * EMB);
  const f32x4 t = *(const f32x4*)(tsrc + l31 * 4);
  const int tgt_item = target[b];

  const int* keysrc = halfsel ? hregion : history;
  const float* table = halfsel ? E_reg : E_hist;

  // --- B-strip column constants ---
  const int col0 = wave * 32;
  float b1v[2], w2v[2];
  #pragma unroll
  for (int n = 0; n < 2; ++n) {
    const int colh = col0 + n * 16 + l15;
    b1v[n] = b1[colh];
    w2v[n] = w2[colh];
  }

  int key[8];
  f32x4 vb[8];

  // ---- prologue: gather + write tile 0 ----
  #pragma unroll
  for (int s = 0; s < 8; ++s)
    key[s] = keysrc[b * NH + wave * 8 + s];
  #pragma unroll
  for (int s = 0; s < 8; ++s)
    vb[s] = *(const f32x4*)(table + (size_t)key[s] * EMB + l31 * 4);
  #pragma unroll
  for (int s = 0; s < 8; ++s) {
    const int row = wave * 8 + s;
    f32x4 v = vb[s] * t;
    float ds = v[0] + v[1] + v[2] + v[3];
    ds += __shfl_xor(ds, 1);
    ds += __shfl_xor(ds, 2);
    ds += __shfl_xor(ds, 4);
    ds += __shfl_xor(ds, 8);
    ds += __shfl_xor(ds, 16);
    ds += __shfl_xor(ds, 32);
    if (lane == 0) dot_lds[0][row] = ds;
    float2 f01; f01.x = v[0]; f01.y = v[1];
    float2 f23; f23.x = v[2]; f23.y = v[3];
    __hip_bfloat162 p0 = __float22bfloat162_rn(f01);
    __hip_bfloat162 p1 = __float22bfloat162_rn(f23);
    union { __hip_bfloat162 h; unsigned u; } c0, c1;
    c0.h = p0; c1.h = p1;
    const int g = halfsel * 16 + (l31 >> 1);
    const int gs = g ^ (row & 7) ^ ((g >> 3) & 3);
    unsigned* dst = (unsigned*)&inp_lds[0][row * 256 + gs * 8 + (lane & 1) * 4];
    dst[0] = c0.u; dst[1] = c1.u;
  }
  __syncthreads();

  float acc_e = 0.f, acc_ed = 0.f;      // wave 7 accumulators

  #pragma unroll
  for (int tt = 0; tt < NT; ++tt) {
    const int cur = tt & 1;

    // issue next-tile key loads (complete long before they're needed)
    if (tt < NT - 1) {
      #pragma unroll
      for (int s = 0; s < 8; ++s)
        key[s] = keysrc[b * NH + (tt + 1) * TROWS + wave * 8 + s];
    }

    // wave 7: fold previous tile's scores while others head into GEMM
    if (tt >= 1 && wave == 7) {
      const int prow = (tt - 1) * TROWS + lane;
      float sc = 0.f;
      #pragma unroll
      for (int w = 0; w < 8; ++w) sc += score_lds[(tt - 1) & 1][w][lane];
      const int item = history[b * NH + prow];
      const float e = (item != tgt_item) ? expf(sc) : 0.f;
      acc_e += e;
      acc_ed += e * dot_lds[tt - 1][lane];
    }

    // ---- GEMM tile tt: wave's 32-col strip, K=256 in 8 steps ----
    f32x4 acc[4][2];
    #pragma unroll
    for (int m = 0; m < 4; ++m)
      #pragma unroll
      for (int n = 0; n < 2; ++n)
        acc[m][n] = (f32x4){0.f, 0.f, 0.f, 0.f};

    #pragma unroll
    for (int kk = 0; kk < 8; ++kk) {
      bf16x8 bfr[2];
      #pragma unroll
      for (int n = 0; n < 2; ++n) {
        const int colh = col0 + n * 16 + l15;
        bfr[n] = *(const bf16x8*)(W1T + (size_t)colh * TWOD + kk * 32 + lhi * 8);
      }
      bf16x8 af[4];
      #pragma unroll
      for (int m = 0; m < 4; ++m) {
        const int row = m * 16 + l15;
        const int gk = kk * 4 + lhi;
        const int gs = gk ^ (row & 7) ^ ((gk >> 3) & 3);
        af[m] = *(const bf16x8*)(&inp_lds[cur][row * 256 + gs * 8]);
      }
      __builtin_amdgcn_s_setprio(1);
      #pragma unroll
      for (int m = 0; m < 4; ++m)
        #pragma unroll
        for (int n = 0; n < 2; ++n)
          acc[m][n] = __builtin_amdgcn_mfma_f32_16x16x32_bf16(af[m], bfr[n], acc[m][n], 0, 0, 0);
      __builtin_amdgcn_s_setprio(0);
    }

    // issue next-tile row gathers NOW (last vmem in flight -> clean in-order
    // retirement; latency hides under the epilogue VALU below)
    if (tt < NT - 1) {
      #pragma unroll
      for (int s = 0; s < 8; ++s)
        vb[s] = *(const f32x4*)(table + (size_t)key[s] * EMB + l31 * 4);
    }

    // ---- epilogue: relu + b1, dot w2, 16-lane reduce -> score_lds ----
    #pragma unroll
    for (int m = 0; m < 4; ++m) {
      #pragma unroll
      for (int r = 0; r < 4; ++r) {
        float p = 0.f;
        #pragma unroll
        for (int n = 0; n < 2; ++n) {
          float hv = acc[m][n][r] + b1v[n];   // C/D: col=lane&15, row=(lane>>4)*4+r
          hv = hv > 0.f ? hv : 0.f;
          p += hv * w2v[n];
        }
        p += __shfl_xor(p, 1);
        p += __shfl_xor(p, 2);
        p += __shfl_xor(p, 4);
        p += __shfl_xor(p, 8);
        if (l15 == 0) score_lds[cur][wave][m * 16 + lhi * 4 + r] = p;
      }
    }

    // ---- convert + write next tile into the other LDS buffer ----
    if (tt < NT - 1) {
      #pragma unroll
      for (int s = 0; s < 8; ++s) {
        const int row = wave * 8 + s;
        f32x4 v = vb[s] * t;
        float ds = v[0] + v[1] + v[2] + v[3];
        ds += __shfl_xor(ds, 1);
        ds += __shfl_xor(ds, 2);
        ds += __shfl_xor(ds, 4);
        ds += __shfl_xor(ds, 8);
        ds += __shfl_xor(ds, 16);
        ds += __shfl_xor(ds, 32);
        if (lane == 0) dot_lds[tt + 1][row] = ds;
        float2 f01; f01.x = v[0]; f01.y = v[1];
        float2 f23; f23.x = v[2]; f23.y = v[3];
        __hip_bfloat162 p0 = __float22bfloat162_rn(f01);
        __hip_bfloat162 p1 = __float22bfloat162_rn(f23);
        union { __hip_bfloat162 h; unsigned u; } c0, c1;
        c0.h = p0; c1.h = p1;
        const int g = halfsel * 16 + (l31 >> 1);
        const int gs = g ^ (row & 7) ^ ((g >> 3) & 3);
        unsigned* dst = (unsigned*)&inp_lds[cur ^ 1][row * 256 + gs * 8 + (lane & 1) * 4];
        dst[0] = c0.u; dst[1] = c1.u;
      }
    }
    __syncthreads();
  }

  // ---- wave 7: fold last tile, reduce, write output ----
  if (wave == 7) {
    const int prow = (NT - 1) * TROWS + lane;
    float sc = 0.f;
    #pragma unroll
    for (int w = 0; w < 8; ++w) sc += score_lds[(NT - 1) & 1][w][lane];
    const int item = history[b * NH + prow];
    const float e = (item != tgt_item) ? expf(sc) : 0.f;
    acc_e += e;
    acc_ed += e * dot_lds[NT - 1][lane];

    float se = acc_e, sd = acc_ed;
    #pragma unroll
    for (int off = 32; off >= 1; off >>= 1) {
      se += __shfl_xor(se, off);
      sd += __shfl_xor(sd, off);
    }
    if (lane == 0) {
      const float pred = (se > 0.f) ? (sd / sqrtf(se)) : 0.f;  // denom = sum^0.5
      out[b] = 1.f / (1.f + expf(-pred));
    }
  }
}

extern "C" void kernel_launch(void* const* d_in, const int* in_sizes, int n_in,
                              void* d_out, int out_size, void* d_ws, size_t ws_size,
                              hipStream_t stream) {
  const int* history = (const int*)d_in[0];
  const int* target  = (const int*)d_in[1];
  const int* hregion = (const int*)d_in[2];
  const int* tregion = (const int*)d_in[3];
  const float* E_hist = (const float*)d_in[4];
  const float* E_targ = (const float*)d_in[5];
  const float* E_reg  = (const float*)d_in[6];
  const float* W1 = (const float*)d_in[7];
  const float* b1 = (const float*)d_in[8];
  const float* w2 = (const float*)d_in[9];
  float* out = (float*)d_out;

  unsigned short* W1T = (unsigned short*)d_ws;

  prep_w1t<<<TWOD, HID, 0, stream>>>(W1, W1T);
  nais_main<<<NB, 512, 0, stream>>>(history, target, hregion, tregion,
                                    E_hist, E_targ, E_reg, W1T, b1, w2, out);
}

// Round 7
// 89.490 us; speedup vs baseline: 1.9872x; 1.1906x over previous
//
#include <hip/hip_runtime.h>
#include <hip/hip_bf16.h>

#define NB 1024
#define NH 256
#define EMB 128
#define TWOD 256
#define HID 256
#define ROWS 128            // history rows per block
#define BPB 2               // blocks per batch element
#define NBLK (NB * BPB)

typedef __attribute__((ext_vector_type(4))) float f32x4;
typedef __attribute__((ext_vector_type(8))) short bf16x8;

__device__ __forceinline__ unsigned short f2bf(float f) {
  union { float f; unsigned u; } v; v.f = f;
  unsigned u = v.u;
  unsigned r = (u + 0x7fffu + ((u >> 16) & 1u)) >> 16;
  return (unsigned short)r;
}

// W1 [d=256][n=256] fp32 -> W1T [n][d] bf16 (B-fragment: n-major, k contiguous)
__global__ __launch_bounds__(256) void prep_w1t(const float* __restrict__ W1,
                                                unsigned short* __restrict__ W1T) {
  const int d = blockIdx.x;
  const int n = threadIdx.x;
  W1T[(size_t)n * TWOD + d] = f2bf(W1[(size_t)d * HID + n]);
}

// 2048 blocks (2 per batch element), 512 threads = 8 waves, 128 rows per block.
// Round-3 structure (the 96us best) with ONE structural change in the GEMM:
// kk is the OUTER loop and both 64-row chunks are processed per kk, so each
// W1T fragment load feeds 16 MFMAs (was 8, loaded twice). The 64 live
// accumulator VGPRs force the allocator off the 64-reg remat tier.
__global__ __launch_bounds__(512, 4) void nais_main(
    const int* __restrict__ history, const int* __restrict__ target,
    const int* __restrict__ hregion, const int* __restrict__ tregion,
    const float* __restrict__ E_hist, const float* __restrict__ E_targ,
    const float* __restrict__ E_reg,
    const unsigned short* __restrict__ W1T, const float* __restrict__ b1,
    const float* __restrict__ w2,
    float* __restrict__ part_se, float* __restrict__ part_sd)
{
  const int blk = blockIdx.x;
  const int b = blk >> 1;
  const int r0 = (blk & 1) * ROWS;      // row offset within the 256-history
  const int tid = threadIdx.x;
  const int lane = tid & 63;
  const int wave = tid >> 6;            // 0..7
  const int l15 = lane & 15;
  const int lhi = lane >> 4;
  const int l31 = lane & 31;
  const int halfsel = lane >> 5;        // 0: E_hist/E_targ half, 1: E_reg half

  __shared__ __align__(16) unsigned short inp_lds[ROWS * 256];  // 64 KiB, swizzled
  __shared__ float dot_lds[ROWS];
  __shared__ int items_lds[ROWS];
  __shared__ float score_parts[8][ROWS];

  // per-lane target vector slice (4 floats), loaded directly
  const float* tsrc = halfsel ? (E_reg + (size_t)tregion[b] * EMB)
                              : (E_targ + (size_t)target[b] * EMB);
  const f32x4 t = *(const f32x4*)(tsrc + l31 * 4);
  const int tgt_item = target[b];

  const int* keysrc = halfsel ? hregion : history;
  const float* table = halfsel ? E_reg : E_hist;

  // ---- Phase 1: coalesced gather + multiply + bf16 tile + row sums ----
  {
    int key[16];
    #pragma unroll
    for (int s = 0; s < 16; ++s)
      key[s] = keysrc[b * NH + r0 + wave * 16 + s];

    f32x4 vb[16];
    #pragma unroll
    for (int s = 0; s < 16; ++s)
      vb[s] = *(const f32x4*)(table + (size_t)key[s] * EMB + l31 * 4);

    #pragma unroll
    for (int s = 0; s < 16; ++s) {
      const int row = wave * 16 + s;
      if (lane == 0) items_lds[row] = key[s];   // lane 0 is halfsel==0 -> item id
      f32x4 v = vb[s] * t;
      float ds = v[0] + v[1] + v[2] + v[3];
      ds += __shfl_xor(ds, 1);
      ds += __shfl_xor(ds, 2);
      ds += __shfl_xor(ds, 4);
      ds += __shfl_xor(ds, 8);
      ds += __shfl_xor(ds, 16);
      ds += __shfl_xor(ds, 32);         // combine E_hist + E_reg halves
      if (lane == 0) dot_lds[row] = ds;

      float2 f01; f01.x = v[0]; f01.y = v[1];
      float2 f23; f23.x = v[2]; f23.y = v[3];
      __hip_bfloat162 p0 = __float22bfloat162_rn(f01);
      __hip_bfloat162 p1 = __float22bfloat162_rn(f23);
      union { __hip_bfloat162 h; unsigned u; } c0, c1;
      c0.h = p0; c1.h = p1;
      const int g = halfsel * 16 + (l31 >> 1);          // 16B granule 0..31
      const int gs = g ^ (row & 7) ^ ((g >> 3) & 3);    // swizzle (bijective/row)
      unsigned* dst = (unsigned*)&inp_lds[row * 256 + gs * 8 + (lane & 1) * 4];
      dst[0] = c0.u; dst[1] = c1.u;
    }
  }
  __syncthreads();

  // ---- Phase 2: GEMM. wave owns cols [wave*32, wave*32+32); kk outer,
  //      both 64-row chunks inner -> each bfr load feeds 16 MFMAs ----
  {
    const int col0 = wave * 32;
    float b1v[2], w2v[2];
    #pragma unroll
    for (int n = 0; n < 2; ++n) {
      const int colh = col0 + n * 16 + l15;
      b1v[n] = b1[colh];
      w2v[n] = w2[colh];
    }

    f32x4 acc[2][4][2];
    #pragma unroll
    for (int c = 0; c < 2; ++c)
      #pragma unroll
      for (int m = 0; m < 4; ++m)
        #pragma unroll
        for (int n = 0; n < 2; ++n)
          acc[c][m][n] = (f32x4){0.f, 0.f, 0.f, 0.f};

    #pragma unroll
    for (int kk = 0; kk < 8; ++kk) {
      bf16x8 bfr[2];
      #pragma unroll
      for (int n = 0; n < 2; ++n) {
        const int colh = col0 + n * 16 + l15;
        bfr[n] = *(const bf16x8*)(W1T + (size_t)colh * TWOD + kk * 32 + lhi * 8);
      }
      bf16x8 af[2][4];
      #pragma unroll
      for (int c = 0; c < 2; ++c)
        #pragma unroll
        for (int m = 0; m < 4; ++m) {
          const int row = c * 64 + m * 16 + l15;
          const int gk = kk * 4 + lhi;
          const int gs = gk ^ (row & 7) ^ ((gk >> 3) & 3);
          af[c][m] = *(const bf16x8*)(&inp_lds[row * 256 + gs * 8]);
        }
      __builtin_amdgcn_s_setprio(1);
      #pragma unroll
      for (int c = 0; c < 2; ++c)
        #pragma unroll
        for (int m = 0; m < 4; ++m)
          #pragma unroll
          for (int n = 0; n < 2; ++n)
            acc[c][m][n] = __builtin_amdgcn_mfma_f32_16x16x32_bf16(af[c][m], bfr[n], acc[c][m][n], 0, 0, 0);
      __builtin_amdgcn_s_setprio(0);
    }

    // epilogue: relu + b1, dot with w2, 16-lane reduce -> score_parts[wave][row]
    #pragma unroll
    for (int c = 0; c < 2; ++c) {
      #pragma unroll
      for (int m = 0; m < 4; ++m) {
        #pragma unroll
        for (int r = 0; r < 4; ++r) {
          float p = 0.f;
          #pragma unroll
          for (int n = 0; n < 2; ++n) {
            float hv = acc[c][m][n][r] + b1v[n];  // C/D: col=lane&15, row=(lane>>4)*4+r
            hv = hv > 0.f ? hv : 0.f;
            p += hv * w2v[n];
          }
          p += __shfl_xor(p, 1);
          p += __shfl_xor(p, 2);
          p += __shfl_xor(p, 4);
          p += __shfl_xor(p, 8);
          if (l15 == 0) score_parts[wave][c * 64 + m * 16 + lhi * 4 + r] = p;
        }
      }
    }
  }
  __syncthreads();

  // ---- Phase 3: masked exp + partial sums -> per-(block,wave) ws slots ----
  if (wave < 2) {
    const int lrow = wave * 64 + lane;
    float sc = 0.f;
    #pragma unroll
    for (int w = 0; w < 8; ++w) sc += score_parts[w][lrow];
    float e = (items_lds[lrow] != tgt_item) ? expf(sc) : 0.f;
    float ed = e * dot_lds[lrow];
    #pragma unroll
    for (int off = 32; off >= 1; off >>= 1) {
      e += __shfl_xor(e, off);
      ed += __shfl_xor(ed, off);
    }
    if (lane == 0) {
      part_se[blk * 2 + wave] = e;
      part_sd[blk * 2 + wave] = ed;
    }
  }
}

__global__ __launch_bounds__(256) void finalize(const float* __restrict__ part_se,
                                                const float* __restrict__ part_sd,
                                                float* __restrict__ out) {
  const int b = blockIdx.x * 256 + threadIdx.x;
  if (b < NB) {
    float se = 0.f, sd = 0.f;
    #pragma unroll
    for (int i = 0; i < BPB * 2; ++i) {
      se += part_se[b * BPB * 2 + i];
      sd += part_sd[b * BPB * 2 + i];
    }
    const float pred = (se > 0.f) ? (sd / sqrtf(se)) : 0.f;  // denom = sum^0.5
    out[b] = 1.f / (1.f + expf(-pred));
  }
}

extern "C" void kernel_launch(void* const* d_in, const int* in_sizes, int n_in,
                              void* d_out, int out_size, void* d_ws, size_t ws_size,
                              hipStream_t stream) {
  const int* history = (const int*)d_in[0];
  const int* target  = (const int*)d_in[1];
  const int* hregion = (const int*)d_in[2];
  const int* tregion = (const int*)d_in[3];
  const float* E_hist = (const float*)d_in[4];
  const float* E_targ = (const float*)d_in[5];
  const float* E_reg  = (const float*)d_in[6];
  const float* W1 = (const float*)d_in[7];
  const float* b1 = (const float*)d_in[8];
  const float* w2 = (const float*)d_in[9];
  float* out = (float*)d_out;

  unsigned short* W1T = (unsigned short*)d_ws;
  char* p = (char*)d_ws + (size_t)TWOD * HID * sizeof(unsigned short);
  float* part_se = (float*)p;        p += (size_t)NBLK * 2 * sizeof(float);
  float* part_sd = (float*)p;

  prep_w1t<<<TWOD, HID, 0, stream>>>(W1, W1T);
  nais_main<<<NBLK, 512, 0, stream>>>(history, target, hregion, tregion,
                                      E_hist, E_targ, E_reg, W1T, b1, w2,
                                      part_se, part_sd);
  finalize<<<(NB + 255) / 256, 256, 0, stream>>>(part_se, part_sd, out);
}